// Round 1
// 982.453 us; speedup vs baseline: 1.2894x; 1.2894x over previous
//
#include <hip/hip_runtime.h>
#include <stdint.h>

#define H     1024
#define K2    2048
#define NTOT  5120
#define BATCH 64
#define BM 128
#define BN 128
#define BK 64

typedef unsigned short u16;
typedef __attribute__((ext_vector_type(8))) short short8;
typedef __attribute__((ext_vector_type(4))) float floatx4;

__device__ __forceinline__ float bf2f(u16 u) {
    return __uint_as_float(((uint32_t)u) << 16);
}
__device__ __forceinline__ u16 f2bf(float f) {
    uint32_t u = __float_as_uint(f);
    u += 0x7fffu + ((u >> 16) & 1u);
    return (u16)(u >> 16);
}
__device__ __forceinline__ uint32_t pk2(float lo, float hi) {
    return (uint32_t)f2bf(lo) | ((uint32_t)f2bf(hi) << 16);
}
__device__ __forceinline__ float sigf(float x) {
    return 1.0f / (1.0f + __expf(-x));
}
__device__ __forceinline__ float tanh_(float x) {
    float e = __expf(-2.0f * fabsf(x));
    float r = (1.0f - e) / (1.0f + e);
    return copysignf(r, x);
}

// ---- pack weights (fp32 in) -> bf16 WT[n][k]; k<1024 from W, else U ----
__global__ void pack_weights(const float* __restrict__ Wio, const float* __restrict__ Uio,
                             const float* __restrict__ Wfl, const float* __restrict__ Ufl,
                             const float* __restrict__ Wfr, const float* __restrict__ Ufr,
                             u16* __restrict__ WT) {
    __shared__ u16 tile[32][33];
    int k0 = blockIdx.x * 32;
    int n0 = blockIdx.y * 32;
    const float *Wp, *Up; int ncols, nloc;
    if (n0 < 3072)      { Wp = Wio; Up = Uio; ncols = 3072; nloc = n0; }
    else if (n0 < 4096) { Wp = Wfl; Up = Ufl; ncols = 1024; nloc = n0 - 3072; }
    else                { Wp = Wfr; Up = Ufr; ncols = 1024; nloc = n0 - 4096; }
    int t = threadIdx.x;
    int c = t & 31, r = t >> 5;
#pragma unroll
    for (int i = 0; i < 4; ++i) {
        int rr = r + i * 8;
        int k = k0 + rr;
        float v = (k < 1024) ? Wp[(long)k * ncols + nloc + c]
                             : Up[(long)(k - 1024) * ncols + nloc + c];
        tile[rr][c] = f2bf(v);
    }
    __syncthreads();
#pragma unroll
    for (int i = 0; i < 4; ++i) {
        int rr = r + i * 8;
        WT[(long)(n0 + rr) * K2 + k0 + c] = tile[c][rr];
    }
}

// ---- leaf gather + fp32->bf16: leaf[node][d] = emb[tokens[node]][d] ----
__global__ void leaf_pack(const int* __restrict__ tokens, const float* __restrict__ emb,
                          u16* __restrict__ leaf) {
    int idx = blockIdx.x * 256 + threadIdx.x;   // 16384 blocks -> 4,194,304 float4
    int node = idx >> 8;
    int d4 = idx & 255;
    int tok = tokens[node];
    float4 v = ((const float4*)emb)[(long)tok * 256 + d4];
    uint2 o; o.x = pk2(v.x, v.y); o.y = pk2(v.z, v.w);
    ((uint2*)leaf)[(long)node * 256 + d4] = o;
}

// ---- GEMM (m97 structure, 128x128) for small row counts ----
__global__ void gemm_bt(const u16* __restrict__ A, const u16* __restrict__ BT,
                        float* __restrict__ G, int mc) {
    __shared__ __align__(16) u16 AsBs[16896];   // 33,792 B; K-loop: As|Bs, epilogue: epi
    u16* As = AsBs;
    u16* Bs = AsBs + 8192;
    float* epi = (float*)AsBs;                  // 64 x 132 fp32
    int tid  = threadIdx.x;
    int lane = tid & 63;
    int w    = tid >> 6;
    int wm   = w >> 1, wn = w & 1;
    int rowTile = blockIdx.x * BM;
    int n0      = blockIdx.y * BN;

    const u16* asrc[4];
    const u16* bsrc[4];
#pragma unroll
    for (int cc = 0; cc < 4; ++cc) {
        int r = cc * 32 + w * 8 + (lane >> 3);
        int j = rowTile + r; if (j >= mc) j = mc - 1;
        asrc[cc] = A + (long)j * K2 + (lane & 7) * 8;
        bsrc[cc] = BT + (long)(n0 + r) * K2 + (lane & 7) * 8;
    }

    floatx4 acc[4][4];
#pragma unroll
    for (int mt = 0; mt < 4; ++mt)
#pragma unroll
        for (int nt = 0; nt < 4; ++nt)
            acc[mt][nt] = (floatx4){0.f, 0.f, 0.f, 0.f};

    for (int k0 = 0; k0 < K2; k0 += BK) {
#pragma unroll
        for (int cc = 0; cc < 4; ++cc) {
            __builtin_amdgcn_global_load_lds(
                (const __attribute__((address_space(1))) void*)(asrc[cc] + k0),
                (__attribute__((address_space(3))) void*)(As + cc * 2048 + w * 512), 16, 0, 0);
            __builtin_amdgcn_global_load_lds(
                (const __attribute__((address_space(1))) void*)(bsrc[cc] + k0),
                (__attribute__((address_space(3))) void*)(Bs + cc * 2048 + w * 512), 16, 0, 0);
        }
        __syncthreads();
#pragma unroll
        for (int kb = 0; kb < 2; ++kb) {
            int kfo = kb * 32 + (lane >> 4) * 8;
            short8 af[4], bfv[4];
#pragma unroll
            for (int mt = 0; mt < 4; ++mt)
                af[mt] = *(const short8*)&As[(wm * 64 + mt * 16 + (lane & 15)) * BK + kfo];
#pragma unroll
            for (int nt = 0; nt < 4; ++nt)
                bfv[nt] = *(const short8*)&Bs[(wn * 64 + nt * 16 + (lane & 15)) * BK + kfo];
#pragma unroll
            for (int mt = 0; mt < 4; ++mt)
#pragma unroll
                for (int nt = 0; nt < 4; ++nt)
                    acc[mt][nt] = __builtin_amdgcn_mfma_f32_16x16x32_bf16(
                        af[mt], bfv[nt], acc[mt][nt], 0, 0, 0);
        }
        __syncthreads();
    }

    // ---- epilogue: LDS round-trip -> fully coalesced float4 stores ----
#pragma unroll
    for (int s = 0; s < 2; ++s) {
        if (wm == s) {
#pragma unroll
            for (int mt = 0; mt < 4; ++mt)
#pragma unroll
                for (int r = 0; r < 4; ++r) {
                    int lrow = mt * 16 + (lane >> 4) * 4 + r;
#pragma unroll
                    for (int nt = 0; nt < 4; ++nt)
                        epi[lrow * 132 + wn * 64 + nt * 16 + (lane & 15)] = acc[mt][nt][r];
                }
        }
        __syncthreads();
        int gr0 = rowTile + s * 64;
#pragma unroll
        for (int k = 0; k < 8; ++k) {
            int f4 = tid + k * 256;     // 0..2047 float4 slots = 64 rows x 32
            int row = f4 >> 5, c4 = f4 & 31;
            if (gr0 + row < mc) {
                float4 v = *(const float4*)&epi[row * 132 + c4 * 4];
                *(float4*)&G[(long)(gr0 + row) * NTOT + n0 + c4 * 4] = v;
            }
        }
        __syncthreads();
    }
}

// ==== 256x256 counted-vmcnt pipelined GEMM (T1+T2+T3/T4+T5) =================
// 512 threads = 8 waves (2M x 4N); per-wave C = 128x64 (8 x 4 frags).
// K-tile = 64, split into two k=32 sub-phases. LDS = 2 buffers x (A 32K + B 32K).
// Per buffer (u16 idx): A0 @0, A1 @8192, B0 @16384, B1 @24576. Subtile = 256 rows
// x 32 u16 (64B rows), swizzled phys_byte = logical ^ ((row&7)<<4) -> 2-way max
// conflicts on ds_read_b128. Stage: linear LDS dest (global_load_lds), inverse-
// swizzled per-lane global source (rule #21).
// Pipeline invariant (per wave, per phase): wait vmcnt(4); barrier; stage next
// tile's sub (4 loads -> other buffer); 12 ds_read_b128; 32 MFMA. 8 loads stay
// in flight across 2 barriers; the 4 drained are exactly this phase's operands.
#define STAGE_HALF(tt, dd, ss)                                                       \
    do {                                                                             \
        __builtin_amdgcn_global_load_lds(                                            \
            (const __attribute__((address_space(1))) void*)(srcA[ss][0] + (tt) * 64),\
            (__attribute__((address_space(3))) void*)(lds + (dd) * 32768 + (ss) * 8192 + w * 512), 16, 0, 0); \
        __builtin_amdgcn_global_load_lds(                                            \
            (const __attribute__((address_space(1))) void*)(srcA[ss][1] + (tt) * 64),\
            (__attribute__((address_space(3))) void*)(lds + (dd) * 32768 + (ss) * 8192 + 4096 + w * 512), 16, 0, 0); \
        __builtin_amdgcn_global_load_lds(                                            \
            (const __attribute__((address_space(1))) void*)(srcB[ss][0] + (tt) * 64),\
            (__attribute__((address_space(3))) void*)(lds + (dd) * 32768 + 16384 + (ss) * 8192 + w * 512), 16, 0, 0); \
        __builtin_amdgcn_global_load_lds(                                            \
            (const __attribute__((address_space(1))) void*)(srcB[ss][1] + (tt) * 64),\
            (__attribute__((address_space(3))) void*)(lds + (dd) * 32768 + 16384 + (ss) * 8192 + 4096 + w * 512), 16, 0, 0); \
    } while (0)

#define PHASE(dd, ss)                                                                \
    do {                                                                             \
        const u16* As_ = lds + (dd) * 32768 + (ss) * 8192;                           \
        const u16* Bs_ = lds + (dd) * 32768 + 16384 + (ss) * 8192;                   \
        short8 af[8], bf[4];                                                         \
        _Pragma("unroll")                                                            \
        for (int mt = 0; mt < 8; ++mt) af[mt] = *(const short8*)&As_[aOff[mt]];      \
        _Pragma("unroll")                                                            \
        for (int nt = 0; nt < 4; ++nt) bf[nt] = *(const short8*)&Bs_[bOff[nt]];      \
        __builtin_amdgcn_s_setprio(1);                                               \
        _Pragma("unroll")                                                            \
        for (int mt = 0; mt < 8; ++mt)                                               \
            _Pragma("unroll")                                                        \
            for (int nt = 0; nt < 4; ++nt)                                           \
                acc[mt][nt] = __builtin_amdgcn_mfma_f32_16x16x32_bf16(               \
                    af[mt], bf[nt], acc[mt][nt], 0, 0, 0);                           \
        __builtin_amdgcn_s_setprio(0);                                               \
    } while (0)

__global__ __launch_bounds__(512, 2) void gemm256(const u16* __restrict__ A,
                                                  const u16* __restrict__ BT,
                                                  float* __restrict__ G, int gm) {
    __shared__ __align__(16) u16 lds[65536];    // 128 KiB -> 1 block/CU
    const int tid  = threadIdx.x;
    const int lane = tid & 63;
    const int w    = tid >> 6;
    const int wm   = w >> 2, wn = w & 3;

    // XCD-bijective swizzle (m204); n-tile fastest inside an XCD chunk so the
    // A panels of a chunk stay L2-resident while WT streams through L3.
    int nwg = gm * 20;
    int f = blockIdx.x;
    int q = nwg >> 3, r = nwg & 7;
    int xcd = f & 7, rank = f >> 3;
    int wg = (xcd < r ? xcd * (q + 1) : r * (q + 1) + (xcd - r) * q) + rank;
    int by = wg % 20;
    int bx = wg / 20;
    long rowTile = (long)bx * 256;
    int n0 = by * 256;

    // per-thread stage sources: phys slot (tid*16 + call*8192) -> logical elem
    // via the inverse of S(a)=a^((a>>6&7)<<4):  a = p^(p8<<6)^(p7<<5)^((p6^p8)<<4)
    const u16* srcA[2][2];
    const u16* srcB[2][2];
#pragma unroll
    for (int c = 0; c < 2; ++c) {
        uint32_t p = (uint32_t)tid * 16u + (uint32_t)c * 8192u;
        uint32_t b8 = (p >> 8) & 1u, b7 = (p >> 7) & 1u, b6 = (p >> 6) & 1u;
        uint32_t a = p ^ (b8 << 6) ^ (b7 << 5) ^ ((b6 ^ b8) << 4);
        int row = (int)(a >> 6);
        int ku  = (int)((a & 63u) >> 1);
#pragma unroll
        for (int s = 0; s < 2; ++s) {
            srcA[s][c] = A  + (rowTile + row) * K2 + s * 32 + ku;
            srcB[s][c] = BT + (long)(n0 + row) * K2 + s * 32 + ku;
        }
    }

    // per-thread swizzled fragment offsets (u16 units) within a subtile
    int aOff[8], bOff[4];
#pragma unroll
    for (int mt = 0; mt < 8; ++mt) {
        int row = wm * 128 + mt * 16 + (lane & 15);
        uint32_t byt = ((uint32_t)row << 6) | (uint32_t)((lane >> 4) << 4);
        aOff[mt] = (int)((byt ^ (uint32_t)((row & 7) << 4)) >> 1);
    }
#pragma unroll
    for (int nt = 0; nt < 4; ++nt) {
        int row = wn * 64 + nt * 16 + (lane & 15);
        uint32_t byt = ((uint32_t)row << 6) | (uint32_t)((lane >> 4) << 4);
        bOff[nt] = (int)((byt ^ (uint32_t)((row & 7) << 4)) >> 1);
    }

    floatx4 acc[8][4];
#pragma unroll
    for (int mt = 0; mt < 8; ++mt)
#pragma unroll
        for (int nt = 0; nt < 4; ++nt)
            acc[mt][nt] = (floatx4){0.f, 0.f, 0.f, 0.f};

    // prologue: stage tile 0 into buffer 0 (A0,B0 first -> the 4 oldest loads)
    STAGE_HALF(0, 0, 0);
    STAGE_HALF(0, 0, 1);

    for (int t = 0; t < 32; ++t) {              // 32 K-tiles of 64
        int d = t & 1;
        asm volatile("s_waitcnt vmcnt(4)" ::: "memory");  // tile t's A0,B0 landed
        asm volatile("s_barrier" ::: "memory");
        if (t < 31) STAGE_HALF(t + 1, d ^ 1, 0);
        PHASE(d, 0);
        if (t < 31) { asm volatile("s_waitcnt vmcnt(4)" ::: "memory"); }  // t's A1,B1
        else        { asm volatile("s_waitcnt vmcnt(0)" ::: "memory"); }  // final drain
        asm volatile("s_barrier" ::: "memory");
        if (t < 31) STAGE_HALF(t + 1, d ^ 1, 1);
        PHASE(d, 1);
    }

    // ---- epilogue: LDS round-trip, 4 slabs of 64 rows, coalesced float4 ----
    __syncthreads();
    float* epi = (float*)lds;                   // 64 x 272 fp32 (stride breaks banks)
#pragma unroll
    for (int s = 0; s < 4; ++s) {
        if (wm == (s >> 1)) {
            int mtb = (s & 1) * 4;
#pragma unroll
            for (int mi = 0; mi < 4; ++mi) {
#pragma unroll
                for (int r = 0; r < 4; ++r) {
                    int lrow = mi * 16 + (lane >> 4) * 4 + r;
#pragma unroll
                    for (int nt = 0; nt < 4; ++nt)
                        epi[lrow * 272 + wn * 64 + nt * 16 + (lane & 15)] =
                            acc[mtb + mi][nt][r];
                }
            }
        }
        __syncthreads();
        long gr0 = rowTile + s * 64;
#pragma unroll
        for (int k = 0; k < 8; ++k) {
            int f4 = tid + k * 512;             // 4096 slots = 64 rows x 64 float4
            int row = f4 >> 6, c4 = f4 & 63;
            float4 v = *(const float4*)&epi[row * 272 + c4 * 4];
            *(float4*)&G[(gr0 + row) * NTOT + n0 + c4 * 4] = v;
        }
        __syncthreads();
    }
}

// ---- gates (float4): c = sig(i)tanh(ck)+sig(fl)cl+sig(fr)cr; h = sig(o)tanh(c) ----
__global__ void gates(const float* __restrict__ G, const float* __restrict__ bio,
                      const float* __restrict__ bfl, const float* __restrict__ bfr,
                      const void* __restrict__ c_in, void* __restrict__ c_out, int c_bf16,
                      float* __restrict__ outF, u16* __restrict__ hnext,
                      int lp, int level_off, int row0, int mc) {
    int idx = blockIdx.x * 256 + threadIdx.x;
    int j = idx >> 8;
    if (j >= mc) return;
    int d = (idx & 255) * 4;
    int J = row0 + j;
    int b = J >> lp, p = J & ((1 << lp) - 1);
    long gb = (long)j * NTOT;
    float4 gi = *(const float4*)&G[gb + d];
    float4 go = *(const float4*)&G[gb + 1024 + d];
    float4 gc = *(const float4*)&G[gb + 2048 + d];
    float4 gl = *(const float4*)&G[gb + 3072 + d];
    float4 gr = *(const float4*)&G[gb + 4096 + d];
    float4 bi = *(const float4*)&bio[d];
    float4 bo = *(const float4*)&bio[1024 + d];
    float4 bc = *(const float4*)&bio[2048 + d];
    float4 bl = *(const float4*)&bfl[d];
    float4 br = *(const float4*)&bfr[d];
    float clv[4] = {0.f, 0.f, 0.f, 0.f}, crv[4] = {0.f, 0.f, 0.f, 0.f};
    if (c_in) {
        long cb = ((long)b * (2 << lp) + 2 * p) * H + d;
        if (c_bf16) {
            uint2 ul = *(const uint2*)((const u16*)c_in + cb);
            uint2 ur = *(const uint2*)((const u16*)c_in + cb + H);
            clv[0] = bf2f((u16)ul.x); clv[1] = bf2f((u16)(ul.x >> 16));
            clv[2] = bf2f((u16)ul.y); clv[3] = bf2f((u16)(ul.y >> 16));
            crv[0] = bf2f((u16)ur.x); crv[1] = bf2f((u16)(ur.x >> 16));
            crv[2] = bf2f((u16)ur.y); crv[3] = bf2f((u16)(ur.y >> 16));
        } else {
            float4 l4 = *(const float4*)((const float*)c_in + cb);
            float4 r4 = *(const float4*)((const float*)c_in + cb + H);
            clv[0] = l4.x; clv[1] = l4.y; clv[2] = l4.z; clv[3] = l4.w;
            crv[0] = r4.x; crv[1] = r4.y; crv[2] = r4.z; crv[3] = r4.w;
        }
    }
    const float* fgi = (const float*)&gi; const float* fgo = (const float*)&go;
    const float* fgc = (const float*)&gc; const float* fgl = (const float*)&gl;
    const float* fgr = (const float*)&gr;
    const float* fbi = (const float*)&bi; const float* fbo = (const float*)&bo;
    const float* fbc = (const float*)&bc; const float* fbl = (const float*)&bl;
    const float* fbr = (const float*)&br;
    float cv[4], hv[4];
    int has_c = (c_in != nullptr);
#pragma unroll
    for (int qq = 0; qq < 4; ++qq) {
        float c = sigf(fgi[qq] + fbi[qq]) * tanh_(fgc[qq] + fbc[qq]);
        if (has_c)
            c += sigf(fgl[qq] + fbl[qq]) * clv[qq] + sigf(fgr[qq] + fbr[qq]) * crv[qq];
        cv[qq] = c;
        hv[qq] = sigf(fgo[qq] + fbo[qq]) * tanh_(c);
    }
    long co = (long)J * H + d;
    if (c_bf16) {
        uint2 oc; oc.x = pk2(cv[0], cv[1]); oc.y = pk2(cv[2], cv[3]);
        *(uint2*)((u16*)c_out + co) = oc;
    } else {
        *(float4*)((float*)c_out + co) = make_float4(cv[0], cv[1], cv[2], cv[3]);
    }
    long oi = ((long)b * 255 + level_off + p) * H + d;
    *(float4*)&outF[oi] = make_float4(hv[0], hv[1], hv[2], hv[3]);
    uint2 oh; oh.x = pk2(hv[0], hv[1]); oh.y = pk2(hv[2], hv[3]);
    *(uint2*)(hnext + (long)J * H + d) = oh;
}

__global__ void root_copy(const float* __restrict__ outF, const void* __restrict__ c_root,
                          int c_bf16, float* __restrict__ tail) {
    int idx = blockIdx.x * 256 + threadIdx.x;   // 131072
    if (idx < 65536) {
        int b = idx >> 10, d = idx & 1023;
        tail[idx] = outF[((long)b * 255 + 254) * H + d];
    } else {
        int i2 = idx - 65536;
        tail[idx] = c_bf16 ? bf2f(((const u16*)c_root)[i2]) : ((const float*)c_root)[i2];
    }
}

extern "C" void kernel_launch(void* const* d_in, const int* in_sizes, int n_in,
                              void* d_out, int out_size, void* d_ws, size_t ws_size,
                              hipStream_t stream) {
    const int* tokens = (const int*)d_in[0];
    const float* emb = (const float*)d_in[1];
    const float* Wio = (const float*)d_in[2];
    const float* bio = (const float*)d_in[3];
    const float* Uio = (const float*)d_in[4];
    const float* Wfl = (const float*)d_in[5];
    const float* bfl = (const float*)d_in[6];
    const float* Ufl = (const float*)d_in[7];
    const float* Wfr = (const float*)d_in[8];
    const float* bfr = (const float*)d_in[9];
    const float* Ufr = (const float*)d_in[10];
    float* outF = (float*)d_out;

    // ---- ws carve (adaptive) ----
    char* ws = (char*)d_ws;
    size_t off = 0;
    u16* WT   = (u16*)(ws + off); off += (size_t)NTOT * K2 * 2;        // 20.97 MB
    u16* leaf = (u16*)(ws + off); off += (size_t)BATCH * 256 * H * 2;  // 33.55 MB
    u16* hE   = (u16*)(ws + off); off += (size_t)8192 * H * 2;         // 16.78 MB
    u16* hO   = (u16*)(ws + off); off += (size_t)4096 * H * 2;         //  8.39 MB
    size_t cEf = (size_t)8192 * H, cOf = (size_t)4096 * H;             // elements
    int c_bf16 = (ws_size >= off + (cEf + cOf) * 4 + (size_t)512 * NTOT * 4) ? 0 : 1;
    size_t csz = c_bf16 ? 2 : 4;
    void* cE = (void*)(ws + off); off += cEf * csz;
    void* cO = (void*)(ws + off); off += cOf * csz;
    size_t avail = (ws_size > off) ? (ws_size - off) : 0;
    long Grows = (long)(avail / ((size_t)NTOT * 4));
    if (Grows > 8192) Grows = 8192;
    Grows &= ~255L;
    if (Grows < 128) Grows = 128;
    float* G = (float*)(ws + off);

    pack_weights<<<dim3(64, 160), 256, 0, stream>>>(Wio, Uio, Wfl, Ufl, Wfr, Ufr, WT);
    leaf_pack<<<16384, 256, 0, stream>>>(tokens, emb, leaf);

    const int off_out[8] = {0, 128, 192, 224, 240, 248, 252, 254};
    for (int li = 0; li < 8; ++li) {
        int lp = 7 - li;
        long m = (long)BATCH << lp;
        const u16* Acur = (li == 0) ? leaf : ((li & 1) ? hE : hO);
        u16* hnext = (li & 1) ? hO : hE;
        const void* c_in = (li == 0) ? nullptr : ((li & 1) ? cE : cO);
        void* c_out = (li & 1) ? cO : cE;
        for (long row0 = 0; row0 < m; row0 += Grows) {
            int mc = (int)((m - row0 > Grows) ? Grows : (m - row0));
            if (mc >= 2048 && (mc & 255) == 0) {
                int gm = mc >> 8;
                gemm256<<<gm * 20, 512, 0, stream>>>(Acur + row0 * K2, WT, G, gm);
            } else {
                dim3 grid((mc + BM - 1) / BM, NTOT / BN);
                gemm_bt<<<grid, 256, 0, stream>>>(Acur + row0 * K2, WT, G, mc);
            }
            gates<<<mc, 256, 0, stream>>>(G, bio, bfl, bfr, c_in, c_out, c_bf16,
                                          outF, hnext, lp, off_out[li], (int)row0, mc);
        }
    }
    root_copy<<<512, 256, 0, stream>>>(outF, cO, c_bf16, outF + (size_t)BATCH * 255 * H);
}

// Round 2
// 974.433 us; speedup vs baseline: 1.3001x; 1.0082x over previous
//
#include <hip/hip_runtime.h>
#include <stdint.h>

#define H     1024
#define K2    2048
#define NTOT  5120
#define BATCH 64
#define BM 128
#define BN 128
#define BK 64

typedef unsigned short u16;
typedef __attribute__((ext_vector_type(8))) short short8;
typedef __attribute__((ext_vector_type(4))) float floatx4;

__device__ __forceinline__ float bf2f(u16 u) {
    return __uint_as_float(((uint32_t)u) << 16);
}
__device__ __forceinline__ u16 f2bf(float f) {
    uint32_t u = __float_as_uint(f);
    u += 0x7fffu + ((u >> 16) & 1u);
    return (u16)(u >> 16);
}
__device__ __forceinline__ uint32_t pk2(float lo, float hi) {
    return (uint32_t)f2bf(lo) | ((uint32_t)f2bf(hi) << 16);
}
__device__ __forceinline__ float sigf(float x) {
    return 1.0f / (1.0f + __expf(-x));
}
__device__ __forceinline__ float tanh_(float x) {
    float e = __expf(-2.0f * fabsf(x));
    float r = (1.0f - e) / (1.0f + e);
    return copysignf(r, x);
}

// ---- pack weights (fp32 in) -> bf16 WT[n][k]; k<1024 from W, else U ----
__global__ void pack_weights(const float* __restrict__ Wio, const float* __restrict__ Uio,
                             const float* __restrict__ Wfl, const float* __restrict__ Ufl,
                             const float* __restrict__ Wfr, const float* __restrict__ Ufr,
                             u16* __restrict__ WT) {
    __shared__ u16 tile[32][33];
    int k0 = blockIdx.x * 32;
    int n0 = blockIdx.y * 32;
    const float *Wp, *Up; int ncols, nloc;
    if (n0 < 3072)      { Wp = Wio; Up = Uio; ncols = 3072; nloc = n0; }
    else if (n0 < 4096) { Wp = Wfl; Up = Ufl; ncols = 1024; nloc = n0 - 3072; }
    else                { Wp = Wfr; Up = Ufr; ncols = 1024; nloc = n0 - 4096; }
    int t = threadIdx.x;
    int c = t & 31, r = t >> 5;
#pragma unroll
    for (int i = 0; i < 4; ++i) {
        int rr = r + i * 8;
        int k = k0 + rr;
        float v = (k < 1024) ? Wp[(long)k * ncols + nloc + c]
                             : Up[(long)(k - 1024) * ncols + nloc + c];
        tile[rr][c] = f2bf(v);
    }
    __syncthreads();
#pragma unroll
    for (int i = 0; i < 4; ++i) {
        int rr = r + i * 8;
        WT[(long)(n0 + rr) * K2 + k0 + c] = tile[c][rr];
    }
}

// ---- leaf gather + fp32->bf16: leaf[node][d] = emb[tokens[node]][d] ----
__global__ void leaf_pack(const int* __restrict__ tokens, const float* __restrict__ emb,
                          u16* __restrict__ leaf) {
    int idx = blockIdx.x * 256 + threadIdx.x;   // 16384 blocks -> 4,194,304 float4
    int node = idx >> 8;
    int d4 = idx & 255;
    int tok = tokens[node];
    float4 v = ((const float4*)emb)[(long)tok * 256 + d4];
    uint2 o; o.x = pk2(v.x, v.y); o.y = pk2(v.z, v.w);
    ((uint2*)leaf)[(long)node * 256 + d4] = o;
}

// ---- GEMM (m97 structure, 128x128) for small row counts ----
__global__ void gemm_bt(const u16* __restrict__ A, const u16* __restrict__ BT,
                        float* __restrict__ G, int mc) {
    __shared__ __align__(16) u16 AsBs[16896];   // 33,792 B; K-loop: As|Bs, epilogue: epi
    u16* As = AsBs;
    u16* Bs = AsBs + 8192;
    float* epi = (float*)AsBs;                  // 64 x 132 fp32
    int tid  = threadIdx.x;
    int lane = tid & 63;
    int w    = tid >> 6;
    int wm   = w >> 1, wn = w & 1;
    int rowTile = blockIdx.x * BM;
    int n0      = blockIdx.y * BN;

    const u16* asrc[4];
    const u16* bsrc[4];
#pragma unroll
    for (int cc = 0; cc < 4; ++cc) {
        int r = cc * 32 + w * 8 + (lane >> 3);
        int j = rowTile + r; if (j >= mc) j = mc - 1;
        asrc[cc] = A + (long)j * K2 + (lane & 7) * 8;
        bsrc[cc] = BT + (long)(n0 + r) * K2 + (lane & 7) * 8;
    }

    floatx4 acc[4][4];
#pragma unroll
    for (int mt = 0; mt < 4; ++mt)
#pragma unroll
        for (int nt = 0; nt < 4; ++nt)
            acc[mt][nt] = (floatx4){0.f, 0.f, 0.f, 0.f};

    for (int k0 = 0; k0 < K2; k0 += BK) {
#pragma unroll
        for (int cc = 0; cc < 4; ++cc) {
            __builtin_amdgcn_global_load_lds(
                (const __attribute__((address_space(1))) void*)(asrc[cc] + k0),
                (__attribute__((address_space(3))) void*)(As + cc * 2048 + w * 512), 16, 0, 0);
            __builtin_amdgcn_global_load_lds(
                (const __attribute__((address_space(1))) void*)(bsrc[cc] + k0),
                (__attribute__((address_space(3))) void*)(Bs + cc * 2048 + w * 512), 16, 0, 0);
        }
        __syncthreads();
#pragma unroll
        for (int kb = 0; kb < 2; ++kb) {
            int kfo = kb * 32 + (lane >> 4) * 8;
            short8 af[4], bfv[4];
#pragma unroll
            for (int mt = 0; mt < 4; ++mt)
                af[mt] = *(const short8*)&As[(wm * 64 + mt * 16 + (lane & 15)) * BK + kfo];
#pragma unroll
            for (int nt = 0; nt < 4; ++nt)
                bfv[nt] = *(const short8*)&Bs[(wn * 64 + nt * 16 + (lane & 15)) * BK + kfo];
#pragma unroll
            for (int mt = 0; mt < 4; ++mt)
#pragma unroll
                for (int nt = 0; nt < 4; ++nt)
                    acc[mt][nt] = __builtin_amdgcn_mfma_f32_16x16x32_bf16(
                        af[mt], bfv[nt], acc[mt][nt], 0, 0, 0);
        }
        __syncthreads();
    }

    // ---- epilogue: LDS round-trip -> fully coalesced float4 stores ----
#pragma unroll
    for (int s = 0; s < 2; ++s) {
        if (wm == s) {
#pragma unroll
            for (int mt = 0; mt < 4; ++mt)
#pragma unroll
                for (int r = 0; r < 4; ++r) {
                    int lrow = mt * 16 + (lane >> 4) * 4 + r;
#pragma unroll
                    for (int nt = 0; nt < 4; ++nt)
                        epi[lrow * 132 + wn * 64 + nt * 16 + (lane & 15)] = acc[mt][nt][r];
                }
        }
        __syncthreads();
        int gr0 = rowTile + s * 64;
#pragma unroll
        for (int k = 0; k < 8; ++k) {
            int f4 = tid + k * 256;     // 0..2047 float4 slots = 64 rows x 32
            int row = f4 >> 5, c4 = f4 & 31;
            if (gr0 + row < mc) {
                float4 v = *(const float4*)&epi[row * 132 + c4 * 4];
                *(float4*)&G[(long)(gr0 + row) * NTOT + n0 + c4 * 4] = v;
            }
        }
        __syncthreads();
    }
}

// ==== 256xBNW counted-vmcnt pipelined GEMM (T1+T2+T3/T4+T5), BNW in {256,320} ====
// 512 threads = 8 waves (2M x 4N); per-wave C = 128 x (BNW/4) (8 x FN frags).
// K-tile = 64 staged WHOLE (NC = 8 or 9 x 16B calls/thread), consumed as two
// k=32 phases. LDS = 2 buffers x (A 32K + B 2*BSUB). Subtile = rows x 32 u16
// (64B rows), swizzled phys_byte = logical ^ ((row&7)<<4). Stage: linear LDS
// dest (global_load_lds) + inverse-swizzled per-lane global source (rule #21).
// Per K-tile: barrier; STAGE(t+1 -> other buf); vmcnt(NC) [tile t landed, t+1
// in flight]; barrier; 2 phases of {FN+8 ds_read_b128, 2x(4xFN) MFMA clusters}.
template <int BNW>
__global__ __launch_bounds__(512, 2) void gemmT(const u16* __restrict__ A,
                                                const u16* __restrict__ BT,
                                                float* __restrict__ G, int gm) {
    constexpr int FN   = BNW / 64;            // n-frags per wave (4 or 5)
    constexpr int NT   = NTOT / BNW;          // n-tiles (20 or 16)
    constexpr int BSUB = BNW * 64;            // bytes per B k-half sub
    constexpr int BUFB = 32768 + 2 * BSUB;    // bytes per buffer (64K or 72K)
    constexpr int BUFU = BUFB / 2;            // u16 per buffer
    constexpr int NC   = BUFB / 8192;         // stage calls/thread/tile (8 or 9)
    constexpr int EPS  = BNW + 8;             // epilogue row stride (floats)
    __shared__ __align__(16) u16 lds[2 * BUFU];

    const int tid  = threadIdx.x;
    const int lane = tid & 63;
    const int w    = tid >> 6;
    const int wm   = w >> 2, wn = w & 3;

    // XCD-bijective swizzle (m204); n-tile fastest within an XCD chunk.
    int nwg = gm * NT;
    int f = blockIdx.x;
    int q = nwg >> 3, r = nwg & 7;
    int xcd = f & 7, rank = f >> 3;
    int wg = (xcd < r ? xcd * (q + 1) : r * (q + 1) + (xcd - r) * q) + rank;
    int by = wg % NT;
    int bx = wg / NT;
    long rowTile = (long)bx * 256;
    int n0 = by * BNW;

    // stage sources: phys slot (c*8192 + tid*16) -> region + inverse swizzle
    const u16* srcP[NC];
#pragma unroll
    for (int c = 0; c < NC; ++c) {
        uint32_t p = (uint32_t)c * 8192u + (uint32_t)tid * 16u;
        uint32_t sub, local; bool isA;
        if (p < 32768u) { isA = true;  sub = p >> 14; local = p & 16383u; }
        else {
            uint32_t pb = p - 32768u;
            isA = false; sub = (pb >= (uint32_t)BSUB) ? 1u : 0u;
            local = pb - sub * (uint32_t)BSUB;
        }
        uint32_t b8 = (local >> 8) & 1u, b7 = (local >> 7) & 1u, b6 = (local >> 6) & 1u;
        uint32_t a = local ^ (b8 << 6) ^ (b7 << 5) ^ ((b6 ^ b8) << 4);
        int row = (int)(a >> 6);
        int kk  = (int)((a & 63u) >> 1);
        srcP[c] = (isA ? A + (rowTile + row) * K2
                       : BT + (long)(n0 + row) * K2) + sub * 32 + kk;
    }

    // per-thread swizzled fragment offsets (u16 units) within a region
    int aOff[8];
#pragma unroll
    for (int mt = 0; mt < 8; ++mt) {
        int row = wm * 128 + mt * 16 + (lane & 15);
        uint32_t byt = ((uint32_t)row << 6) | (uint32_t)((lane >> 4) << 4);
        aOff[mt] = (int)((byt ^ (uint32_t)((row & 7) << 4)) >> 1);
    }
    int bOff[FN];
#pragma unroll
    for (int nt = 0; nt < FN; ++nt) {
        int row = wn * (FN * 16) + nt * 16 + (lane & 15);
        uint32_t byt = ((uint32_t)row << 6) | (uint32_t)((lane >> 4) << 4);
        bOff[nt] = (int)((byt ^ (uint32_t)((row & 7) << 4)) >> 1);
    }

    floatx4 acc[8][FN];
#pragma unroll
    for (int mt = 0; mt < 8; ++mt)
#pragma unroll
        for (int nt = 0; nt < FN; ++nt)
            acc[mt][nt] = (floatx4){0.f, 0.f, 0.f, 0.f};

#define STAGE_T(tt, dd)                                                              \
    _Pragma("unroll")                                                                \
    for (int c = 0; c < NC; ++c)                                                     \
        __builtin_amdgcn_global_load_lds(                                            \
            (const __attribute__((address_space(1))) void*)(srcP[c] + (tt) * 64),    \
            (__attribute__((address_space(3))) void*)(lds + (dd) * BUFU + c * 4096 + tid * 8), 16, 0, 0)

#define PHASE_T(dd, ss)                                                              \
    do {                                                                             \
        const u16* As_ = lds + (dd) * BUFU + (ss) * 8192;                            \
        const u16* Bs_ = lds + (dd) * BUFU + 16384 + (ss) * (BSUB / 2);              \
        short8 bfr_[FN];                                                             \
        _Pragma("unroll")                                                            \
        for (int nt = 0; nt < FN; ++nt) bfr_[nt] = *(const short8*)&Bs_[bOff[nt]];   \
        _Pragma("unroll")                                                            \
        for (int hh = 0; hh < 2; ++hh) {                                             \
            short8 af_[4];                                                           \
            _Pragma("unroll")                                                        \
            for (int m2 = 0; m2 < 4; ++m2)                                           \
                af_[m2] = *(const short8*)&As_[aOff[hh * 4 + m2]];                   \
            __builtin_amdgcn_s_setprio(1);                                           \
            _Pragma("unroll")                                                        \
            for (int m2 = 0; m2 < 4; ++m2)                                           \
                _Pragma("unroll")                                                    \
                for (int nt = 0; nt < FN; ++nt)                                      \
                    acc[hh * 4 + m2][nt] = __builtin_amdgcn_mfma_f32_16x16x32_bf16(  \
                        af_[m2], bfr_[nt], acc[hh * 4 + m2][nt], 0, 0, 0);           \
            __builtin_amdgcn_s_setprio(0);                                           \
        }                                                                            \
    } while (0)

    // prologue: stage tile 0 into buffer 0
    STAGE_T(0, 0);

    for (int t = 0; t < 32; ++t) {              // 32 K-tiles of 64
        int d = t & 1;
        asm volatile("s_barrier" ::: "memory");             // prev reads of buf d^1 done
        if (t < 31) {
            STAGE_T(t + 1, d ^ 1);
            asm volatile("s_waitcnt vmcnt(%0)" :: "i"(NC) : "memory");  // tile t landed
        } else {
            asm volatile("s_waitcnt vmcnt(0)" ::: "memory");            // final drain
        }
        asm volatile("s_barrier" ::: "memory");             // all waves: tile t ready
        PHASE_T(d, 0);
        PHASE_T(d, 1);
    }

#undef STAGE_T
#undef PHASE_T

    // ---- epilogue: LDS round-trip, 4 slabs of 64 rows, coalesced float4 ----
    __syncthreads();
    float* epi = (float*)lds;                   // 64 x EPS fp32
#pragma unroll
    for (int s = 0; s < 4; ++s) {
        if (wm == (s >> 1)) {
            int mtb = (s & 1) * 4;
#pragma unroll
            for (int mi = 0; mi < 4; ++mi) {
#pragma unroll
                for (int rr = 0; rr < 4; ++rr) {
                    int lrow = mi * 16 + (lane >> 4) * 4 + rr;
#pragma unroll
                    for (int nt = 0; nt < FN; ++nt)
                        epi[lrow * EPS + wn * (FN * 16) + nt * 16 + (lane & 15)] =
                            acc[mtb + mi][nt][rr];
                }
            }
        }
        __syncthreads();
        long gr0 = rowTile + s * 64;
#pragma unroll
        for (int k = 0; k < BNW / 32; ++k) {
            int f4 = tid + k * 512;             // 16*BNW slots = 64 rows x BNW/4 f4
            int row = f4 / (BNW / 4), c4 = f4 % (BNW / 4);
            float4 v = *(const float4*)&epi[row * EPS + c4 * 4];
            *(float4*)&G[(gr0 + row) * NTOT + n0 + c4 * 4] = v;
        }
        __syncthreads();
    }
}

// ---- gates (float4): c = sig(i)tanh(ck)+sig(fl)cl+sig(fr)cr; h = sig(o)tanh(c) ----
__global__ void gates(const float* __restrict__ G, const float* __restrict__ bio,
                      const float* __restrict__ bfl, const float* __restrict__ bfr,
                      const void* __restrict__ c_in, void* __restrict__ c_out, int c_bf16,
                      float* __restrict__ outF, u16* __restrict__ hnext,
                      int lp, int level_off, int row0, int mc) {
    int idx = blockIdx.x * 256 + threadIdx.x;
    int j = idx >> 8;
    if (j >= mc) return;
    int d = (idx & 255) * 4;
    int J = row0 + j;
    int b = J >> lp, p = J & ((1 << lp) - 1);
    long gb = (long)j * NTOT;
    float4 gi = *(const float4*)&G[gb + d];
    float4 go = *(const float4*)&G[gb + 1024 + d];
    float4 gc = *(const float4*)&G[gb + 2048 + d];
    float4 gl = *(const float4*)&G[gb + 3072 + d];
    float4 gr = *(const float4*)&G[gb + 4096 + d];
    float4 bi = *(const float4*)&bio[d];
    float4 bo = *(const float4*)&bio[1024 + d];
    float4 bc = *(const float4*)&bio[2048 + d];
    float4 bl = *(const float4*)&bfl[d];
    float4 br = *(const float4*)&bfr[d];
    float clv[4] = {0.f, 0.f, 0.f, 0.f}, crv[4] = {0.f, 0.f, 0.f, 0.f};
    if (c_in) {
        long cb = ((long)b * (2 << lp) + 2 * p) * H + d;
        if (c_bf16) {
            uint2 ul = *(const uint2*)((const u16*)c_in + cb);
            uint2 ur = *(const uint2*)((const u16*)c_in + cb + H);
            clv[0] = bf2f((u16)ul.x); clv[1] = bf2f((u16)(ul.x >> 16));
            clv[2] = bf2f((u16)ul.y); clv[3] = bf2f((u16)(ul.y >> 16));
            crv[0] = bf2f((u16)ur.x); crv[1] = bf2f((u16)(ur.x >> 16));
            crv[2] = bf2f((u16)ur.y); crv[3] = bf2f((u16)(ur.y >> 16));
        } else {
            float4 l4 = *(const float4*)((const float*)c_in + cb);
            float4 r4 = *(const float4*)((const float*)c_in + cb + H);
            clv[0] = l4.x; clv[1] = l4.y; clv[2] = l4.z; clv[3] = l4.w;
            crv[0] = r4.x; crv[1] = r4.y; crv[2] = r4.z; crv[3] = r4.w;
        }
    }
    const float* fgi = (const float*)&gi; const float* fgo = (const float*)&go;
    const float* fgc = (const float*)&gc; const float* fgl = (const float*)&gl;
    const float* fgr = (const float*)&gr;
    const float* fbi = (const float*)&bi; const float* fbo = (const float*)&bo;
    const float* fbc = (const float*)&bc; const float* fbl = (const float*)&bl;
    const float* fbr = (const float*)&br;
    float cv[4], hv[4];
    int has_c = (c_in != nullptr);
#pragma unroll
    for (int qq = 0; qq < 4; ++qq) {
        float c = sigf(fgi[qq] + fbi[qq]) * tanh_(fgc[qq] + fbc[qq]);
        if (has_c)
            c += sigf(fgl[qq] + fbl[qq]) * clv[qq] + sigf(fgr[qq] + fbr[qq]) * crv[qq];
        cv[qq] = c;
        hv[qq] = sigf(fgo[qq] + fbo[qq]) * tanh_(c);
    }
    long co = (long)J * H + d;
    if (c_bf16) {
        uint2 oc; oc.x = pk2(cv[0], cv[1]); oc.y = pk2(cv[2], cv[3]);
        *(uint2*)((u16*)c_out + co) = oc;
    } else {
        *(float4*)((float*)c_out + co) = make_float4(cv[0], cv[1], cv[2], cv[3]);
    }
    long oi = ((long)b * 255 + level_off + p) * H + d;
    *(float4*)&outF[oi] = make_float4(hv[0], hv[1], hv[2], hv[3]);
    uint2 oh; oh.x = pk2(hv[0], hv[1]); oh.y = pk2(hv[2], hv[3]);
    *(uint2*)(hnext + (long)J * H + d) = oh;
}

__global__ void root_copy(const float* __restrict__ outF, const void* __restrict__ c_root,
                          int c_bf16, float* __restrict__ tail) {
    int idx = blockIdx.x * 256 + threadIdx.x;   // 131072
    if (idx < 65536) {
        int b = idx >> 10, d = idx & 1023;
        tail[idx] = outF[((long)b * 255 + 254) * H + d];
    } else {
        int i2 = idx - 65536;
        tail[idx] = c_bf16 ? bf2f(((const u16*)c_root)[i2]) : ((const float*)c_root)[i2];
    }
}

extern "C" void kernel_launch(void* const* d_in, const int* in_sizes, int n_in,
                              void* d_out, int out_size, void* d_ws, size_t ws_size,
                              hipStream_t stream) {
    const int* tokens = (const int*)d_in[0];
    const float* emb = (const float*)d_in[1];
    const float* Wio = (const float*)d_in[2];
    const float* bio = (const float*)d_in[3];
    const float* Uio = (const float*)d_in[4];
    const float* Wfl = (const float*)d_in[5];
    const float* bfl = (const float*)d_in[6];
    const float* Ufl = (const float*)d_in[7];
    const float* Wfr = (const float*)d_in[8];
    const float* bfr = (const float*)d_in[9];
    const float* Ufr = (const float*)d_in[10];
    float* outF = (float*)d_out;

    // ---- ws carve (adaptive) ----
    char* ws = (char*)d_ws;
    size_t off = 0;
    u16* WT   = (u16*)(ws + off); off += (size_t)NTOT * K2 * 2;        // 20.97 MB
    u16* leaf = (u16*)(ws + off); off += (size_t)BATCH * 256 * H * 2;  // 33.55 MB
    u16* hE   = (u16*)(ws + off); off += (size_t)8192 * H * 2;         // 16.78 MB
    u16* hO   = (u16*)(ws + off); off += (size_t)4096 * H * 2;         //  8.39 MB
    size_t cEf = (size_t)8192 * H, cOf = (size_t)4096 * H;             // elements
    int c_bf16 = (ws_size >= off + (cEf + cOf) * 4 + (size_t)512 * NTOT * 4) ? 0 : 1;
    size_t csz = c_bf16 ? 2 : 4;
    void* cE = (void*)(ws + off); off += cEf * csz;
    void* cO = (void*)(ws + off); off += cOf * csz;
    size_t avail = (ws_size > off) ? (ws_size - off) : 0;
    long Grows = (long)(avail / ((size_t)NTOT * 4));
    if (Grows > 8192) Grows = 8192;
    Grows &= ~255L;
    if (Grows < 128) Grows = 128;
    float* G = (float*)(ws + off);

    pack_weights<<<dim3(64, 160), 256, 0, stream>>>(Wio, Uio, Wfl, Ufl, Wfr, Ufr, WT);
    leaf_pack<<<16384, 256, 0, stream>>>(tokens, emb, leaf);

    const int off_out[8] = {0, 128, 192, 224, 240, 248, 252, 254};
    for (int li = 0; li < 8; ++li) {
        int lp = 7 - li;
        long m = (long)BATCH << lp;
        const u16* Acur = (li == 0) ? leaf : ((li & 1) ? hE : hO);
        u16* hnext = (li & 1) ? hO : hE;
        const void* c_in = (li == 0) ? nullptr : ((li & 1) ? cE : cO);
        void* c_out = (li & 1) ? cO : cE;
        for (long row0 = 0; row0 < m; row0 += Grows) {
            int mc = (int)((m - row0 > Grows) ? Grows : (m - row0));
            if (mc >= 2048 && (mc & 255) == 0) {
                int gm = mc >> 8;
                int b320 = gm * 16, b256 = gm * 20;
                // makespan units: rounds(256) x per-block cost (BN/64)
                int cost320 = ((b320 + 255) >> 8) * 5;
                int cost256 = ((b256 + 255) >> 8) * 4;
                if (cost320 < cost256)
                    gemmT<320><<<b320, 512, 0, stream>>>(Acur + row0 * K2, WT, G, gm);
                else
                    gemmT<256><<<b256, 512, 0, stream>>>(Acur + row0 * K2, WT, G, gm);
            } else {
                dim3 grid((mc + BM - 1) / BM, NTOT / BN);
                gemm_bt<<<grid, 256, 0, stream>>>(Acur + row0 * K2, WT, G, mc);
            }
            gates<<<mc, 256, 0, stream>>>(G, bio, bfl, bfr, c_in, c_out, c_bf16,
                                          outF, hnext, lp, off_out[li], (int)row0, mc);
        }
    }
    root_copy<<<512, 256, 0, stream>>>(outF, cO, c_bf16, outF + (size_t)BATCH * 255 * H);
}

// Round 3
// 948.251 us; speedup vs baseline: 1.3360x; 1.0276x over previous
//
#include <hip/hip_runtime.h>
#include <stdint.h>

#define H     1024
#define K2    2048
#define NTOT  5120
#define BATCH 64
#define BM 128
#define BN 128
#define BK 64

typedef unsigned short u16;
typedef __attribute__((ext_vector_type(8))) short short8;
typedef __attribute__((ext_vector_type(4))) float floatx4;

__device__ __forceinline__ float bf2f(u16 u) {
    return __uint_as_float(((uint32_t)u) << 16);
}
__device__ __forceinline__ u16 f2bf(float f) {
    uint32_t u = __float_as_uint(f);
    u += 0x7fffu + ((u >> 16) & 1u);
    return (u16)(u >> 16);
}
__device__ __forceinline__ uint32_t pk2(float lo, float hi) {
    return (uint32_t)f2bf(lo) | ((uint32_t)f2bf(hi) << 16);
}
__device__ __forceinline__ float sigf(float x) {
    return 1.0f / (1.0f + __expf(-x));
}
__device__ __forceinline__ float tanh_(float x) {
    float e = __expf(-2.0f * fabsf(x));
    float r = (1.0f - e) / (1.0f + e);
    return copysignf(r, x);
}

// ---- pack weights (fp32 in) -> bf16 WT[n][k]; k<1024 from W, else U ----
__global__ void pack_weights(const float* __restrict__ Wio, const float* __restrict__ Uio,
                             const float* __restrict__ Wfl, const float* __restrict__ Ufl,
                             const float* __restrict__ Wfr, const float* __restrict__ Ufr,
                             u16* __restrict__ WT) {
    __shared__ u16 tile[32][33];
    int k0 = blockIdx.x * 32;
    int n0 = blockIdx.y * 32;
    const float *Wp, *Up; int ncols, nloc;
    if (n0 < 3072)      { Wp = Wio; Up = Uio; ncols = 3072; nloc = n0; }
    else if (n0 < 4096) { Wp = Wfl; Up = Ufl; ncols = 1024; nloc = n0 - 3072; }
    else                { Wp = Wfr; Up = Ufr; ncols = 1024; nloc = n0 - 4096; }
    int t = threadIdx.x;
    int c = t & 31, r = t >> 5;
#pragma unroll
    for (int i = 0; i < 4; ++i) {
        int rr = r + i * 8;
        int k = k0 + rr;
        float v = (k < 1024) ? Wp[(long)k * ncols + nloc + c]
                             : Up[(long)(k - 1024) * ncols + nloc + c];
        tile[rr][c] = f2bf(v);
    }
    __syncthreads();
#pragma unroll
    for (int i = 0; i < 4; ++i) {
        int rr = r + i * 8;
        WT[(long)(n0 + rr) * K2 + k0 + c] = tile[c][rr];
    }
}

// ---- leaf gather + fp32->bf16: leaf[node][d] = emb[tokens[node]][d] ----
__global__ void leaf_pack(const int* __restrict__ tokens, const float* __restrict__ emb,
                          u16* __restrict__ leaf) {
    int idx = blockIdx.x * 256 + threadIdx.x;   // 16384 blocks -> 4,194,304 float4
    int node = idx >> 8;
    int d4 = idx & 255;
    int tok = tokens[node];
    float4 v = ((const float4*)emb)[(long)tok * 256 + d4];
    uint2 o; o.x = pk2(v.x, v.y); o.y = pk2(v.z, v.w);
    ((uint2*)leaf)[(long)node * 256 + d4] = o;
}

// ---- GEMM (m97 structure, 128x128) for small row counts ----
__global__ void gemm_bt(const u16* __restrict__ A, const u16* __restrict__ BT,
                        float* __restrict__ G, int mc) {
    __shared__ __align__(16) u16 AsBs[16896];   // 33,792 B; K-loop: As|Bs, epilogue: epi
    u16* As = AsBs;
    u16* Bs = AsBs + 8192;
    float* epi = (float*)AsBs;                  // 64 x 132 fp32
    int tid  = threadIdx.x;
    int lane = tid & 63;
    int w    = tid >> 6;
    int wm   = w >> 1, wn = w & 1;
    int rowTile = blockIdx.x * BM;
    int n0      = blockIdx.y * BN;

    const u16* asrc[4];
    const u16* bsrc[4];
#pragma unroll
    for (int cc = 0; cc < 4; ++cc) {
        int r = cc * 32 + w * 8 + (lane >> 3);
        int j = rowTile + r; if (j >= mc) j = mc - 1;
        asrc[cc] = A + (long)j * K2 + (lane & 7) * 8;
        bsrc[cc] = BT + (long)(n0 + r) * K2 + (lane & 7) * 8;
    }

    floatx4 acc[4][4];
#pragma unroll
    for (int mt = 0; mt < 4; ++mt)
#pragma unroll
        for (int nt = 0; nt < 4; ++nt)
            acc[mt][nt] = (floatx4){0.f, 0.f, 0.f, 0.f};

    for (int k0 = 0; k0 < K2; k0 += BK) {
#pragma unroll
        for (int cc = 0; cc < 4; ++cc) {
            __builtin_amdgcn_global_load_lds(
                (const __attribute__((address_space(1))) void*)(asrc[cc] + k0),
                (__attribute__((address_space(3))) void*)(As + cc * 2048 + w * 512), 16, 0, 0);
            __builtin_amdgcn_global_load_lds(
                (const __attribute__((address_space(1))) void*)(bsrc[cc] + k0),
                (__attribute__((address_space(3))) void*)(Bs + cc * 2048 + w * 512), 16, 0, 0);
        }
        __syncthreads();
#pragma unroll
        for (int kb = 0; kb < 2; ++kb) {
            int kfo = kb * 32 + (lane >> 4) * 8;
            short8 af[4], bfv[4];
#pragma unroll
            for (int mt = 0; mt < 4; ++mt)
                af[mt] = *(const short8*)&As[(wm * 64 + mt * 16 + (lane & 15)) * BK + kfo];
#pragma unroll
            for (int nt = 0; nt < 4; ++nt)
                bfv[nt] = *(const short8*)&Bs[(wn * 64 + nt * 16 + (lane & 15)) * BK + kfo];
#pragma unroll
            for (int mt = 0; mt < 4; ++mt)
#pragma unroll
                for (int nt = 0; nt < 4; ++nt)
                    acc[mt][nt] = __builtin_amdgcn_mfma_f32_16x16x32_bf16(
                        af[mt], bfv[nt], acc[mt][nt], 0, 0, 0);
        }
        __syncthreads();
    }

    // ---- epilogue: LDS round-trip -> fully coalesced float4 stores ----
#pragma unroll
    for (int s = 0; s < 2; ++s) {
        if (wm == s) {
#pragma unroll
            for (int mt = 0; mt < 4; ++mt)
#pragma unroll
                for (int r = 0; r < 4; ++r) {
                    int lrow = mt * 16 + (lane >> 4) * 4 + r;
#pragma unroll
                    for (int nt = 0; nt < 4; ++nt)
                        epi[lrow * 132 + wn * 64 + nt * 16 + (lane & 15)] = acc[mt][nt][r];
                }
        }
        __syncthreads();
        int gr0 = rowTile + s * 64;
#pragma unroll
        for (int k = 0; k < 8; ++k) {
            int f4 = tid + k * 256;     // 0..2047 float4 slots = 64 rows x 32
            int row = f4 >> 5, c4 = f4 & 31;
            if (gr0 + row < mc) {
                float4 v = *(const float4*)&epi[row * 132 + c4 * 4];
                *(float4*)&G[(long)(gr0 + row) * NTOT + n0 + c4 * 4] = v;
            }
        }
        __syncthreads();
    }
}

// ==== 256x256 8-phase pipelined GEMM (m201-style: T1+T2+T3/T4+T5) ============
// 512 threads = 8 waves. Wave (wm=w>>2, wn=w&3) owns C rows {wm*64..+63} u
// {128+wm*64..+63}, cols {wn*32..+31} u {128+wn*32..+31} -> each C-quadrant
// (mh,nh) needs only A-half mh and B-half nh BLOCK-WIDE.
// LDS: 2 dbuf x [A0|A1|B0|B1] slots (16KB each; 2x 8KB k=32 regions).
// Region layout: 128 rows x 64B, swizzled phys = logical ^ ((row&7)<<4);
// staged via linear-dest global_load_lds + inverse-swizzled global src.
// Per tile t (dbuf d=t&1), 4 phases; each: {vmcnt; barrier; ds_reads; stage 1
// half of tile t+1 -> dbuf d^1; setprio(1); 16 MFMA; setprio(0); barrier}.
// FIFO (per wave, 2 loads/stage): entering P0 queue=[A0,B0,B1,A1]x2=8.
// P0: vmcnt(4) drains A0,B0 (read here); stage A0' -> 6.
// P1: vmcnt(4) drains B1 (read here);   stage B0' -> 6.
// P2: vmcnt(4) drains A1 (read here);   stage B1' -> 6.
// P3: no wait;                          stage A1' -> 8.  Last tile: 4/2/0.
#define GP_STAGE(T1, DD, SLOT)                                                       \
    do {                                                                             \
        _Pragma("unroll")                                                            \
        for (int rg = 0; rg < 2; ++rg)                                               \
            __builtin_amdgcn_global_load_lds(                                        \
                (const __attribute__((address_space(1))) void*)(srcS[SLOT][rg] + (T1) * 64), \
                (__attribute__((address_space(3))) void*)(lds + (DD) * 32768 + (SLOT) * 8192 + rg * 4096 + tid * 8), \
                16, 0, 0);                                                           \
    } while (0)

#define GP_MFMA(MB, NB, AF, BF)                                                      \
    do {                                                                             \
        __builtin_amdgcn_s_setprio(1);                                               \
        _Pragma("unroll")                                                            \
        for (int ks = 0; ks < 2; ++ks)                                               \
            _Pragma("unroll")                                                        \
            for (int m2 = 0; m2 < 4; ++m2)                                           \
                _Pragma("unroll")                                                    \
                for (int n2 = 0; n2 < 2; ++n2)                                       \
                    acc[(MB) + m2][(NB) + n2] = __builtin_amdgcn_mfma_f32_16x16x32_bf16( \
                        AF[ks][m2], BF[ks][n2], acc[(MB) + m2][(NB) + n2], 0, 0, 0); \
        __builtin_amdgcn_s_setprio(0);                                               \
    } while (0)

#define GP_TILE(T, D, LASTQ)                                                         \
    do {                                                                             \
        const u16* ldsD = lds + (D) * 32768;                                         \
        /* ---- P0: quadrant (0,0) ---- */                                           \
        asm volatile("s_waitcnt vmcnt(4)" ::: "memory");                             \
        asm volatile("s_barrier" ::: "memory");                                      \
        _Pragma("unroll")                                                            \
        for (int ks = 0; ks < 2; ++ks) {                                             \
            _Pragma("unroll")                                                        \
            for (int m2 = 0; m2 < 4; ++m2)                                           \
                aF[ks][m2] = *(const short8*)&ldsD[aOffP[m2] + ks * 4096];           \
            _Pragma("unroll")                                                        \
            for (int n2 = 0; n2 < 2; ++n2)                                           \
                b0F[ks][n2] = *(const short8*)&ldsD[bOffP[n2] + ks * 4096];          \
        }                                                                            \
        if (!(LASTQ)) GP_STAGE((T) + 1, (D) ^ 1, 0);                                 \
        GP_MFMA(0, 0, aF, b0F);                                                      \
        asm volatile("s_barrier" ::: "memory");                                      \
        /* ---- P1: quadrant (0,1) ---- */                                           \
        if (!(LASTQ)) asm volatile("s_waitcnt vmcnt(4)" ::: "memory");               \
        else          asm volatile("s_waitcnt vmcnt(2)" ::: "memory");               \
        asm volatile("s_barrier" ::: "memory");                                      \
        _Pragma("unroll")                                                            \
        for (int ks = 0; ks < 2; ++ks)                                               \
            _Pragma("unroll")                                                        \
            for (int n2 = 0; n2 < 2; ++n2)                                           \
                b1F[ks][n2] = *(const short8*)&ldsD[bOffP[2 + n2] + ks * 4096];      \
        if (!(LASTQ)) GP_STAGE((T) + 1, (D) ^ 1, 2);                                 \
        GP_MFMA(0, 2, aF, b1F);                                                      \
        asm volatile("s_barrier" ::: "memory");                                      \
        /* ---- P2: quadrant (1,0) ---- */                                           \
        if (!(LASTQ)) asm volatile("s_waitcnt vmcnt(4)" ::: "memory");               \
        else          asm volatile("s_waitcnt vmcnt(0)" ::: "memory");               \
        asm volatile("s_barrier" ::: "memory");                                      \
        _Pragma("unroll")                                                            \
        for (int ks = 0; ks < 2; ++ks)                                               \
            _Pragma("unroll")                                                        \
            for (int m2 = 0; m2 < 4; ++m2)                                           \
                aF[ks][m2] = *(const short8*)&ldsD[aOffP[4 + m2] + ks * 4096];       \
        if (!(LASTQ)) GP_STAGE((T) + 1, (D) ^ 1, 3);                                 \
        GP_MFMA(4, 0, aF, b0F);                                                      \
        asm volatile("s_barrier" ::: "memory");                                      \
        /* ---- P3: quadrant (1,1) ---- */                                           \
        if (!(LASTQ)) GP_STAGE((T) + 1, (D) ^ 1, 1);                                 \
        GP_MFMA(4, 2, aF, b1F);                                                      \
        asm volatile("s_barrier" ::: "memory");                                      \
    } while (0)

__global__ __launch_bounds__(512, 2) void gemmP(const u16* __restrict__ A,
                                                const u16* __restrict__ BT,
                                                float* __restrict__ G, int gm) {
    __shared__ __align__(16) u16 lds[65536];    // 128 KiB -> 1 block/CU
    const int tid  = threadIdx.x;
    const int lane = tid & 63;
    const int w    = tid >> 6;
    const int wm   = w >> 2, wn = w & 3;

    // XCD-bijective swizzle (m204); n-tile fastest within an XCD chunk.
    int nwg = gm * 20;
    int f = blockIdx.x;
    int q = nwg >> 3, r = nwg & 7;
    int xcd = f & 7, rank = f >> 3;
    int wg = (xcd < r ? xcd * (q + 1) : r * (q + 1) + (xcd - r) * q) + rank;
    int by = wg % 20;
    int bx = wg / 20;
    long rowTile = (long)bx * 256;
    int n0 = by * 256;

    // stage sources: 4 slots {A0,A1,B0,B1} x 2 k-regions; per-region phys byte
    // p = tid*16, inverse-swizzled (S(inv(p)) = p, S(a)=a^(((a>>6)&7)<<4)).
    const u16* srcS[4][2];
    {
        uint32_t p = (uint32_t)tid * 16u;
        uint32_t b8 = (p >> 8) & 1u, b7 = (p >> 7) & 1u, b6 = (p >> 6) & 1u;
        uint32_t a = p ^ (b8 << 6) ^ (b7 << 5) ^ ((b6 ^ b8) << 4);
        int row = (int)(a >> 6);            // 0..127 within half
        int kk  = (int)((a & 63u) >> 1);    // u16 within k=32 region
#pragma unroll
        for (int rg = 0; rg < 2; ++rg) {
            srcS[0][rg] = A  + (rowTile + row) * K2 + rg * 32 + kk;          // A0
            srcS[1][rg] = A  + (rowTile + 128 + row) * K2 + rg * 32 + kk;    // A1
            srcS[2][rg] = BT + (long)(n0 + row) * K2 + rg * 32 + kk;         // B0
            srcS[3][rg] = BT + (long)(n0 + 128 + row) * K2 + rg * 32 + kk;   // B1
        }
    }

    // swizzled fragment offsets (u16, region ks=0; +4096 for ks=1)
    int aOffP[8];
#pragma unroll
    for (int mt = 0; mt < 8; ++mt) {
        int hh = mt >> 2;
        int row = wm * 64 + (mt & 3) * 16 + (lane & 15);    // 0..127 in half
        uint32_t byt = ((uint32_t)row << 6) | (uint32_t)((lane >> 4) << 4);
        aOffP[mt] = hh * 8192 + (int)((byt ^ (uint32_t)((row & 7) << 4)) >> 1);
    }
    int bOffP[4];
#pragma unroll
    for (int nt = 0; nt < 4; ++nt) {
        int hh = nt >> 1;
        int row = wn * 32 + (nt & 1) * 16 + (lane & 15);    // 0..127 in half
        uint32_t byt = ((uint32_t)row << 6) | (uint32_t)((lane >> 4) << 4);
        bOffP[nt] = 16384 + hh * 8192 + (int)((byt ^ (uint32_t)((row & 7) << 4)) >> 1);
    }

    floatx4 acc[8][4];
#pragma unroll
    for (int mt = 0; mt < 8; ++mt)
#pragma unroll
        for (int nt = 0; nt < 4; ++nt)
            acc[mt][nt] = (floatx4){0.f, 0.f, 0.f, 0.f};

    short8 aF[2][4], b0F[2][2], b1F[2][2];

    // prologue: stage tile 0 into dbuf 0 in consume order A0,B0,B1,A1
    GP_STAGE(0, 0, 0);
    GP_STAGE(0, 0, 2);
    GP_STAGE(0, 0, 3);
    GP_STAGE(0, 0, 1);

    for (int t = 0; t < 31; ++t) {
        GP_TILE(t, t & 1, 0);
    }
    GP_TILE(31, 1, 1);

    // ---- epilogue: LDS round-trip, 4 slabs of 64 rows, coalesced float4 ----
    // slab s = (mt>>2)*2 + wm; EPS=260 -> row-quarters offset 16 banks (free).
    __syncthreads();
    float* epi = (float*)lds;
#pragma unroll
    for (int s = 0; s < 4; ++s) {
        if (wm == (s & 1)) {
            int mtb = (s >> 1) * 4;
#pragma unroll
            for (int mi = 0; mi < 4; ++mi) {
#pragma unroll
                for (int rr = 0; rr < 4; ++rr) {
                    int lrow = mi * 16 + (lane >> 4) * 4 + rr;
#pragma unroll
                    for (int nt = 0; nt < 4; ++nt) {
                        int col = (nt >> 1) * 128 + wn * 32 + (nt & 1) * 16 + (lane & 15);
                        epi[lrow * 260 + col] = acc[mtb + mi][nt][rr];
                    }
                }
            }
        }
        __syncthreads();
        long gr0 = rowTile + s * 64;
#pragma unroll
        for (int k = 0; k < 8; ++k) {
            int f4 = tid + k * 512;             // 4096 slots = 64 rows x 64 float4
            int row = f4 >> 6, c4 = f4 & 63;
            float4 v = *(const float4*)&epi[row * 260 + c4 * 4];
            *(float4*)&G[(gr0 + row) * NTOT + n0 + c4 * 4] = v;
        }
        __syncthreads();
    }
}

#undef GP_STAGE
#undef GP_MFMA
#undef GP_TILE

// ---- gates (float4): c = sig(i)tanh(ck)+sig(fl)cl+sig(fr)cr; h = sig(o)tanh(c) ----
__global__ void gates(const float* __restrict__ G, const float* __restrict__ bio,
                      const float* __restrict__ bfl, const float* __restrict__ bfr,
                      const void* __restrict__ c_in, void* __restrict__ c_out, int c_bf16,
                      float* __restrict__ outF, u16* __restrict__ hnext,
                      int lp, int level_off, int row0, int mc) {
    int idx = blockIdx.x * 256 + threadIdx.x;
    int j = idx >> 8;
    if (j >= mc) return;
    int d = (idx & 255) * 4;
    int J = row0 + j;
    int b = J >> lp, p = J & ((1 << lp) - 1);
    long gb = (long)j * NTOT;
    float4 gi = *(const float4*)&G[gb + d];
    float4 go = *(const float4*)&G[gb + 1024 + d];
    float4 gc = *(const float4*)&G[gb + 2048 + d];
    float4 gl = *(const float4*)&G[gb + 3072 + d];
    float4 gr = *(const float4*)&G[gb + 4096 + d];
    float4 bi = *(const float4*)&bio[d];
    float4 bo = *(const float4*)&bio[1024 + d];
    float4 bc = *(const float4*)&bio[2048 + d];
    float4 bl = *(const float4*)&bfl[d];
    float4 br = *(const float4*)&bfr[d];
    float clv[4] = {0.f, 0.f, 0.f, 0.f}, crv[4] = {0.f, 0.f, 0.f, 0.f};
    if (c_in) {
        long cb = ((long)b * (2 << lp) + 2 * p) * H + d;
        if (c_bf16) {
            uint2 ul = *(const uint2*)((const u16*)c_in + cb);
            uint2 ur = *(const uint2*)((const u16*)c_in + cb + H);
            clv[0] = bf2f((u16)ul.x); clv[1] = bf2f((u16)(ul.x >> 16));
            clv[2] = bf2f((u16)ul.y); clv[3] = bf2f((u16)(ul.y >> 16));
            crv[0] = bf2f((u16)ur.x); crv[1] = bf2f((u16)(ur.x >> 16));
            crv[2] = bf2f((u16)ur.y); crv[3] = bf2f((u16)(ur.y >> 16));
        } else {
            float4 l4 = *(const float4*)((const float*)c_in + cb);
            float4 r4 = *(const float4*)((const float*)c_in + cb + H);
            clv[0] = l4.x; clv[1] = l4.y; clv[2] = l4.z; clv[3] = l4.w;
            crv[0] = r4.x; crv[1] = r4.y; crv[2] = r4.z; crv[3] = r4.w;
        }
    }
    const float* fgi = (const float*)&gi; const float* fgo = (const float*)&go;
    const float* fgc = (const float*)&gc; const float* fgl = (const float*)&gl;
    const float* fgr = (const float*)&gr;
    const float* fbi = (const float*)&bi; const float* fbo = (const float*)&bo;
    const float* fbc = (const float*)&bc; const float* fbl = (const float*)&bl;
    const float* fbr = (const float*)&br;
    float cv[4], hv[4];
    int has_c = (c_in != nullptr);
#pragma unroll
    for (int qq = 0; qq < 4; ++qq) {
        float c = sigf(fgi[qq] + fbi[qq]) * tanh_(fgc[qq] + fbc[qq]);
        if (has_c)
            c += sigf(fgl[qq] + fbl[qq]) * clv[qq] + sigf(fgr[qq] + fbr[qq]) * crv[qq];
        cv[qq] = c;
        hv[qq] = sigf(fgo[qq] + fbo[qq]) * tanh_(c);
    }
    long co = (long)J * H + d;
    if (c_bf16) {
        uint2 oc; oc.x = pk2(cv[0], cv[1]); oc.y = pk2(cv[2], cv[3]);
        *(uint2*)((u16*)c_out + co) = oc;
    } else {
        *(float4*)((float*)c_out + co) = make_float4(cv[0], cv[1], cv[2], cv[3]);
    }
    long oi = ((long)b * 255 + level_off + p) * H + d;
    *(float4*)&outF[oi] = make_float4(hv[0], hv[1], hv[2], hv[3]);
    uint2 oh; oh.x = pk2(hv[0], hv[1]); oh.y = pk2(hv[2], hv[3]);
    *(uint2*)(hnext + (long)J * H + d) = oh;
}

__global__ void root_copy(const float* __restrict__ outF, const void* __restrict__ c_root,
                          int c_bf16, float* __restrict__ tail) {
    int idx = blockIdx.x * 256 + threadIdx.x;   // 131072
    if (idx < 65536) {
        int b = idx >> 10, d = idx & 1023;
        tail[idx] = outF[((long)b * 255 + 254) * H + d];
    } else {
        int i2 = idx - 65536;
        tail[idx] = c_bf16 ? bf2f(((const u16*)c_root)[i2]) : ((const float*)c_root)[i2];
    }
}

extern "C" void kernel_launch(void* const* d_in, const int* in_sizes, int n_in,
                              void* d_out, int out_size, void* d_ws, size_t ws_size,
                              hipStream_t stream) {
    const int* tokens = (const int*)d_in[0];
    const float* emb = (const float*)d_in[1];
    const float* Wio = (const float*)d_in[2];
    const float* bio = (const float*)d_in[3];
    const float* Uio = (const float*)d_in[4];
    const float* Wfl = (const float*)d_in[5];
    const float* bfl = (const float*)d_in[6];
    const float* Ufl = (const float*)d_in[7];
    const float* Wfr = (const float*)d_in[8];
    const float* bfr = (const float*)d_in[9];
    const float* Ufr = (const float*)d_in[10];
    float* outF = (float*)d_out;

    // ---- ws carve (adaptive) ----
    char* ws = (char*)d_ws;
    size_t off = 0;
    u16* WT   = (u16*)(ws + off); off += (size_t)NTOT * K2 * 2;        // 20.97 MB
    u16* leaf = (u16*)(ws + off); off += (size_t)BATCH * 256 * H * 2;  // 33.55 MB
    u16* hE   = (u16*)(ws + off); off += (size_t)8192 * H * 2;         // 16.78 MB
    u16* hO   = (u16*)(ws + off); off += (size_t)4096 * H * 2;         //  8.39 MB
    size_t cEf = (size_t)8192 * H, cOf = (size_t)4096 * H;             // elements
    int c_bf16 = (ws_size >= off + (cEf + cOf) * 4 + (size_t)512 * NTOT * 4) ? 0 : 1;
    size_t csz = c_bf16 ? 2 : 4;
    void* cE = (void*)(ws + off); off += cEf * csz;
    void* cO = (void*)(ws + off); off += cOf * csz;
    size_t avail = (ws_size > off) ? (ws_size - off) : 0;
    long Grows = (long)(avail / ((size_t)NTOT * 4));
    if (Grows > 8192) Grows = 8192;
    Grows &= ~255L;
    if (Grows < 128) Grows = 128;
    float* G = (float*)(ws + off);

    pack_weights<<<dim3(64, 160), 256, 0, stream>>>(Wio, Uio, Wfl, Ufl, Wfr, Ufr, WT);
    leaf_pack<<<16384, 256, 0, stream>>>(tokens, emb, leaf);

    const int off_out[8] = {0, 128, 192, 224, 240, 248, 252, 254};
    for (int li = 0; li < 8; ++li) {
        int lp = 7 - li;
        long m = (long)BATCH << lp;
        const u16* Acur = (li == 0) ? leaf : ((li & 1) ? hE : hO);
        u16* hnext = (li & 1) ? hO : hE;
        const void* c_in = (li == 0) ? nullptr : ((li & 1) ? cE : cO);
        void* c_out = (li & 1) ? cO : cE;
        for (long row0 = 0; row0 < m; row0 += Grows) {
            int mc = (int)((m - row0 > Grows) ? Grows : (m - row0));
            if (mc >= 1024 && (mc & 255) == 0) {
                int gm = mc >> 8;
                gemmP<<<gm * 20, 512, 0, stream>>>(Acur + row0 * K2, WT, G, gm);
            } else {
                dim3 grid((mc + BM - 1) / BM, NTOT / BN);
                gemm_bt<<<grid, 256, 0, stream>>>(Acur + row0 * K2, WT, G, mc);
            }
            gates<<<mc, 256, 0, stream>>>(G, bio, bfl, bfr, c_in, c_out, c_bf16,
                                          outF, hnext, lp, off_out[li], (int)row0, mc);
        }
    }
    root_copy<<<512, 256, 0, stream>>>(outF, cO, c_bf16, outF + (size_t)BATCH * 255 * H);
}